// Round 2
// baseline (1843.580 us; speedup 1.0000x reference)
//
#include <hip/hip_runtime.h>

// Fused Conv1d(k=3,pad=1) + BN(inference) + 4-step LIF + residual.
// x: (L=2048, TB=128, D=128) f32. conv_w: (D,D,3). out: (L,TB,D) f32.
//
// R4: x moves from LDS-broadcast to the SCALAR path. All lanes of a wave
// share (l, n, i) -> x addresses are wave-uniform (forced via
// readfirstlane(tid>>6)) -> s_load into SGPRs, consumed as the 1-SGPR
// operand of v_fma_f32. Eliminates xs LDS (33.8 KB), its staging pass
// and barrier. LDS = double-buffered weight tile only (26.6 KB), one
// barrier per it with reg-prefetch of the next tile. FMA order is
// bit-identical to R3 (absmax must stay 0.0).

constexpr int L   = 2048;
constexpr int NTB = 128;
constexpr int D   = 128;
constexpr int T   = 4;
constexpr int LT  = 64;        // l-tile per block (4 waves x JT)
constexpr int JT  = 16;        // l-positions per thread
constexpr int IT  = 8;         // input channels per weight tile
constexpr int WROW = 52;       // paired w row: o0 @ [0,24), pad, o1 @ [28,52)

__device__ __forceinline__ float4 ldx(const float* __restrict__ x, int l, int n, int cb) {
    // l is wave-uniform. Clamped address (always in-bounds) + uniform zero select.
    const int lc = (l < 0) ? 0 : ((l >= L) ? (L - 1) : l);
    float4 v = ((const float4*)x)[(lc * NTB + n) * (D / 4) + cb];
    if (l < 0 || l >= L) v = make_float4(0.f, 0.f, 0.f, 0.f);
    return v;
}

__global__ __launch_bounds__(256, 3)
void snn_conv_lif(const float* __restrict__ x, const float* __restrict__ w,
                  const float* __restrict__ gamma, const float* __restrict__ beta,
                  const float* __restrict__ mean, const float* __restrict__ var,
                  float* __restrict__ out) {
    __shared__ float ws[2][64 * WROW];   // 26624 B total

    const int tid = threadIdx.x;
    const int b   = blockIdx.x & 31;
    const int lt  = blockIdx.x >> 5;
    const int l0  = lt * LT;
    const int q   = tid & 63;                                  // o-pair index
    const int lh  = __builtin_amdgcn_readfirstlane(tid >> 6);  // wave id, FORCED uniform
    const int p0  = lh * JT;
    const int lb  = l0 - 1 + p0;                               // uniform l base

    const int o0 = 2 * q, o1 = o0 + 1;
    const float sc0 = gamma[o0] / sqrtf(var[o0] + 1e-5f);
    const float bi0 = beta[o0] - mean[o0] * sc0;
    const float sc1 = gamma[o1] / sqrtf(var[o1] + 1e-5f);
    const float bi1 = beta[o1] - mean[o1] * sc1;

    // weight staging map: thread -> 3 consecutive float4 of a 12-float4 row-pair
    // (no integer division; layout identical to R3's ws)
    const int qq = tid >> 2;
    const int r3 = 3 * (tid & 3);
    int grow[3], lrow[3];
    #pragma unroll
    for (int c = 0; c < 3; ++c) {
        const int rr = r3 + c;
        const int oo = (rr >= 6) ? 1 : 0;
        const int c6 = rr - 6 * oo;
        grow[c] = (2 * qq + oo) * (D * 3) + c6 * 4;   // global float offset (+ it*24)
        lrow[c] = qq * WROW + oo * 28 + c6 * 4;       // lds float offset
    }

    float v0[JT], v1[JT];
    #pragma unroll
    for (int j = 0; j < JT; ++j) { v0[j] = 0.f; v1[j] = 0.f; }

    #pragma unroll 1
    for (int t = 0; t < T; ++t) {
        const int n = t * 32 + b;

        // ---- stage tile it=0 into ws[0] ----
        #pragma unroll
        for (int c = 0; c < 3; ++c) {
            const float4 wv = *((const float4*)(w + grow[c]));
            *((float4*)(&ws[0][lrow[c]])) = wv;
        }
        __syncthreads();

        float a0[JT], a1[JT];
        #pragma unroll
        for (int j = 0; j < JT; ++j) { a0[j] = 0.f; a1[j] = 0.f; }

        #pragma unroll 1
        for (int it = 0; it < D / IT; ++it) {
            const int cur = it & 1;

            // prefetch next weight tile to regs (latency hides under compute)
            float4 wp[3];
            if (it < 15) {
                #pragma unroll
                for (int c = 0; c < 3; ++c)
                    wp[c] = *((const float4*)(w + grow[c] + (it + 1) * (IT * 3)));
            }

            const float* wrow = &ws[cur][q * WROW];
            #pragma unroll
            for (int i4 = 0; i4 < IT / 4; ++i4) {
                const float4 wa0 = *((const float4*)(wrow + i4 * 12));
                const float4 wa1 = *((const float4*)(wrow + i4 * 12 + 4));
                const float4 wa2 = *((const float4*)(wrow + i4 * 12 + 8));
                const float4 wb0 = *((const float4*)(wrow + 28 + i4 * 12));
                const float4 wb1 = *((const float4*)(wrow + 28 + i4 * 12 + 4));
                const float4 wb2 = *((const float4*)(wrow + 28 + i4 * 12 + 8));
                const float wA[12] = {wa0.x, wa0.y, wa0.z, wa0.w,
                                      wa1.x, wa1.y, wa1.z, wa1.w,
                                      wa2.x, wa2.y, wa2.z, wa2.w};
                const float wB[12] = {wb0.x, wb0.y, wb0.z, wb0.w,
                                      wb1.x, wb1.y, wb1.z, wb1.w,
                                      wb2.x, wb2.y, wb2.z, wb2.w};

                const int cb = it * 2 + i4;            // float4 channel-group
                float4 xa = ldx(x, lb + 0, n, cb);
                float4 xb = ldx(x, lb + 1, n, cb);
                #pragma unroll
                for (int j = 0; j < JT; ++j) {
                    const float4 xc = ldx(x, lb + j + 2, n, cb);
                    float s0 = a0[j];
                    float s1 = a1[j];
                    s0 = fmaf(xa.x, wA[0], s0);   s1 = fmaf(xa.x, wB[0], s1);   // k=0,i+0
                    s0 = fmaf(xa.y, wA[3], s0);   s1 = fmaf(xa.y, wB[3], s1);   // k=0,i+1
                    s0 = fmaf(xa.z, wA[6], s0);   s1 = fmaf(xa.z, wB[6], s1);
                    s0 = fmaf(xa.w, wA[9], s0);   s1 = fmaf(xa.w, wB[9], s1);
                    s0 = fmaf(xb.x, wA[1], s0);   s1 = fmaf(xb.x, wB[1], s1);   // k=1
                    s0 = fmaf(xb.y, wA[4], s0);   s1 = fmaf(xb.y, wB[4], s1);
                    s0 = fmaf(xb.z, wA[7], s0);   s1 = fmaf(xb.z, wB[7], s1);
                    s0 = fmaf(xb.w, wA[10], s0);  s1 = fmaf(xb.w, wB[10], s1);
                    s0 = fmaf(xc.x, wA[2], s0);   s1 = fmaf(xc.x, wB[2], s1);   // k=2
                    s0 = fmaf(xc.y, wA[5], s0);   s1 = fmaf(xc.y, wB[5], s1);
                    s0 = fmaf(xc.z, wA[8], s0);   s1 = fmaf(xc.z, wB[8], s1);
                    s0 = fmaf(xc.w, wA[11], s0);  s1 = fmaf(xc.w, wB[11], s1);
                    a0[j] = s0; a1[j] = s1;
                    xa = xb; xb = xc;
                }
            }

            // write prefetched tile into the other buffer; single barrier per it
            if (it < 15) {
                #pragma unroll
                for (int c = 0; c < 3; ++c)
                    *((float4*)(&ws[cur ^ 1][lrow[c]])) = wp[c];
            }
            __syncthreads();
        }

        // ---- BN + LIF step + residual + store (float2 over the o-pair) ----
        #pragma unroll
        for (int j = 0; j < JT; ++j) {
            const float y0 = fmaf(a0[j], sc0, bi0);
            const float y1 = fmaf(a1[j], sc1, bi1);
            const float h0 = 0.5f * (v0[j] + y0);      // v + (y - v)/tau, tau=2
            const float h1 = 0.5f * (v1[j] + y1);
            const bool f0 = (h0 >= 1.0f);
            const bool f1 = (h1 >= 1.0f);
            v0[j] = f0 ? 0.0f : h0;                    // hard reset
            v1[j] = f1 ? 0.0f : h1;
            const int l = l0 + p0 + j;
            const float2 res = ((const float2*)x)[(l * NTB + n) * (D / 2) + q];
            float2 ov;
            ov.x = res.x + (f0 ? 1.0f : 0.0f);
            ov.y = res.y + (f1 ? 1.0f : 0.0f);
            ((float2*)out)[(l * NTB + n) * (D / 2) + q] = ov;
        }
    }
}

extern "C" void kernel_launch(void* const* d_in, const int* in_sizes, int n_in,
                              void* d_out, int out_size, void* d_ws, size_t ws_size,
                              hipStream_t stream) {
    const float* x     = (const float*)d_in[0];
    const float* w     = (const float*)d_in[1];
    const float* gamma = (const float*)d_in[2];
    const float* beta  = (const float*)d_in[3];
    const float* mean  = (const float*)d_in[4];
    const float* var   = (const float*)d_in[5];
    float* out = (float*)d_out;

    dim3 grid((L / LT) * 32);   // 32 l-tiles x 32 b values = 1024 blocks
    dim3 block(256);
    snn_conv_lif<<<grid, block, 0, stream>>>(x, w, gamma, beta, mean, var, out);
}

// Round 3
// 1336.707 us; speedup vs baseline: 1.3792x; 1.3792x over previous
//
#include <hip/hip_runtime.h>

// Fused Conv1d(k=3,pad=1) + BN(inference) + 4-step LIF + residual.
// x: (L=2048, TB=128, D=128) f32. conv_w: (D,D,3). out: (L,TB,D) f32.
//
// R5: revert to R3's LDS structure (R4's scalar-path x failed: latency-bound),
// then hoist t into the accumulators. it-loop is outermost: each weight tile
// staged ONCE per block (was 4x), x staged as per-it 8-channel slices for all
// 4 n's. acc[4t][2o][8l] = 64 regs; LIF scan runs in the epilogue only.
// Barriers 128 -> 32/block, LDS 47KB -> 17.7KB, target 4 blocks/CU.
// FMA order per (o,l,t) bit-identical to R3 (absmax must stay 0.0).

constexpr int L   = 2048;
constexpr int NTB = 128;
constexpr int D   = 128;
constexpr int T   = 4;
constexpr int LT  = 32;        // l-tile per block (4 wave-groups x JT)
constexpr int NP  = LT + 2;    // 34 staged positions (halo)
constexpr int JT  = 8;         // l-positions per thread
constexpr int IT  = 8;         // input channels per weight tile
constexpr int WROW = 52;       // paired w row: o0 @ [0,24), pad, o1 @ [28,52)
constexpr int XROW = 8;        // floats per (n,pos) x-slice

__global__ __launch_bounds__(256, 4)
void snn_conv_lif(const float* __restrict__ x, const float* __restrict__ w,
                  const float* __restrict__ gamma, const float* __restrict__ beta,
                  const float* __restrict__ mean, const float* __restrict__ var,
                  float* __restrict__ out) {
    __shared__ float ws[64 * WROW];        // 13312 B
    __shared__ float xs[T][NP * XROW];     // 4352 B   (total 17664 B)

    const int tid = threadIdx.x;
    const int b   = blockIdx.x & 31;
    const int lt  = blockIdx.x >> 5;
    const int l0  = lt * LT;
    const int q   = tid & 63;          // o-pair index
    const int lh  = tid >> 6;          // l-group
    const int p0  = lh * JT;

    const int o0 = 2 * q, o1 = o0 + 1;
    const float sc0 = gamma[o0] / sqrtf(var[o0] + 1e-5f);
    const float bi0 = beta[o0] - mean[o0] * sc0;
    const float sc1 = gamma[o1] / sqrtf(var[o1] + 1e-5f);
    const float bi1 = beta[o1] - mean[o1] * sc1;

    // weight staging map: thread -> 3 consecutive float4 of a 12-float4 row-pair
    const int qq = tid >> 2;
    const int r3 = 3 * (tid & 3);
    int grow[3], lrow[3];
    #pragma unroll
    for (int c = 0; c < 3; ++c) {
        const int rr = r3 + c;
        const int oo = (rr >= 6) ? 1 : 0;
        const int c6 = rr - 6 * oo;
        grow[c] = (2 * qq + oo) * (D * 3) + c6 * 4;   // + it*24 per tile
        lrow[c] = qq * WROW + oo * 28 + c6 * 4;
    }

    // x staging map: 272 float4 items (pos 0..33, nt 0..3, half 0..1)
    // item idx -> pos = idx>>3, nt = (idx>>1)&3, half = idx&1

    float a0[T][JT], a1[T][JT];
    #pragma unroll
    for (int t = 0; t < T; ++t)
        #pragma unroll
        for (int j = 0; j < JT; ++j) { a0[t][j] = 0.f; a1[t][j] = 0.f; }

    #pragma unroll 1
    for (int it = 0; it < D / IT; ++it) {
        __syncthreads();   // previous tile's readers done before overwrite
        // ---- stage weight tile ----
        #pragma unroll
        for (int c = 0; c < 3; ++c)
            *((float4*)(ws + lrow[c])) = *((const float4*)(w + grow[c] + it * (IT * 3)));
        // ---- stage x 8-channel slices for all 4 n ----
        #pragma unroll
        for (int rep = 0; rep < 2; ++rep) {
            const int idx = tid + rep * 256;
            if (idx < NP * 8) {
                const int pos  = idx >> 3;
                const int nt   = (idx >> 1) & 3;
                const int half = idx & 1;
                const int l = l0 - 1 + pos;
                const int n = nt * 32 + b;
                float4 val = make_float4(0.f, 0.f, 0.f, 0.f);
                if (l >= 0 && l < L)
                    val = ((const float4*)x)[(l * NTB + n) * (D / 4) + it * 2 + half];
                ((float4*)(&xs[nt][pos * XROW]))[half] = val;
            }
        }
        __syncthreads();

        const float* wrow = ws + q * WROW;
        #pragma unroll
        for (int i4 = 0; i4 < IT / 4; ++i4) {
            const float4 wa0 = *((const float4*)(wrow + i4 * 12));
            const float4 wa1 = *((const float4*)(wrow + i4 * 12 + 4));
            const float4 wa2 = *((const float4*)(wrow + i4 * 12 + 8));
            const float4 wb0 = *((const float4*)(wrow + 28 + i4 * 12));
            const float4 wb1 = *((const float4*)(wrow + 28 + i4 * 12 + 4));
            const float4 wb2 = *((const float4*)(wrow + 28 + i4 * 12 + 8));
            const float wA[12] = {wa0.x, wa0.y, wa0.z, wa0.w,
                                  wa1.x, wa1.y, wa1.z, wa1.w,
                                  wa2.x, wa2.y, wa2.z, wa2.w};
            const float wB[12] = {wb0.x, wb0.y, wb0.z, wb0.w,
                                  wb1.x, wb1.y, wb1.z, wb1.w,
                                  wb2.x, wb2.y, wb2.z, wb2.w};
            #pragma unroll
            for (int nt = 0; nt < T; ++nt) {
                const float4* xc4 = (const float4*)(&xs[nt][0]);
                float4 xa = xc4[(p0 + 0) * 2 + i4];
                float4 xb = xc4[(p0 + 1) * 2 + i4];
                #pragma unroll
                for (int j = 0; j < JT; ++j) {
                    const float4 xc = xc4[(p0 + j + 2) * 2 + i4];
                    float s0 = a0[nt][j];
                    float s1 = a1[nt][j];
                    s0 = fmaf(xa.x, wA[0], s0);   s1 = fmaf(xa.x, wB[0], s1);   // k=0,i+0
                    s0 = fmaf(xa.y, wA[3], s0);   s1 = fmaf(xa.y, wB[3], s1);   // k=0,i+1
                    s0 = fmaf(xa.z, wA[6], s0);   s1 = fmaf(xa.z, wB[6], s1);
                    s0 = fmaf(xa.w, wA[9], s0);   s1 = fmaf(xa.w, wB[9], s1);
                    s0 = fmaf(xb.x, wA[1], s0);   s1 = fmaf(xb.x, wB[1], s1);   // k=1
                    s0 = fmaf(xb.y, wA[4], s0);   s1 = fmaf(xb.y, wB[4], s1);
                    s0 = fmaf(xb.z, wA[7], s0);   s1 = fmaf(xb.z, wB[7], s1);
                    s0 = fmaf(xb.w, wA[10], s0);  s1 = fmaf(xb.w, wB[10], s1);
                    s0 = fmaf(xc.x, wA[2], s0);   s1 = fmaf(xc.x, wB[2], s1);   // k=2
                    s0 = fmaf(xc.y, wA[5], s0);   s1 = fmaf(xc.y, wB[5], s1);
                    s0 = fmaf(xc.z, wA[8], s0);   s1 = fmaf(xc.z, wB[8], s1);
                    s0 = fmaf(xc.w, wA[11], s0);  s1 = fmaf(xc.w, wB[11], s1);
                    a0[nt][j] = s0; a1[nt][j] = s1;
                    xa = xb; xb = xc;
                }
            }
        }
    }

    // ---- epilogue: BN + sequential LIF over t + residual + store ----
    float v0[JT], v1[JT];
    #pragma unroll
    for (int j = 0; j < JT; ++j) { v0[j] = 0.f; v1[j] = 0.f; }

    #pragma unroll
    for (int t = 0; t < T; ++t) {
        const int n = t * 32 + b;
        #pragma unroll
        for (int j = 0; j < JT; ++j) {
            const float y0 = fmaf(a0[t][j], sc0, bi0);
            const float y1 = fmaf(a1[t][j], sc1, bi1);
            const float h0 = 0.5f * (v0[j] + y0);      // v + (y - v)/tau, tau=2
            const float h1 = 0.5f * (v1[j] + y1);
            const bool f0 = (h0 >= 1.0f);
            const bool f1 = (h1 >= 1.0f);
            v0[j] = f0 ? 0.0f : h0;                    // hard reset
            v1[j] = f1 ? 0.0f : h1;
            const int l = l0 + p0 + j;
            const float2 res = ((const float2*)x)[(l * NTB + n) * (D / 2) + q];
            float2 ov;
            ov.x = res.x + (f0 ? 1.0f : 0.0f);
            ov.y = res.y + (f1 ? 1.0f : 0.0f);
            ((float2*)out)[(l * NTB + n) * (D / 2) + q] = ov;
        }
    }
}

extern "C" void kernel_launch(void* const* d_in, const int* in_sizes, int n_in,
                              void* d_out, int out_size, void* d_ws, size_t ws_size,
                              hipStream_t stream) {
    const float* x     = (const float*)d_in[0];
    const float* w     = (const float*)d_in[1];
    const float* gamma = (const float*)d_in[2];
    const float* beta  = (const float*)d_in[3];
    const float* mean  = (const float*)d_in[4];
    const float* var   = (const float*)d_in[5];
    float* out = (float*)d_out;

    dim3 grid((L / LT) * 32);   // 64 l-tiles x 32 b values = 2048 blocks
    dim3 block(256);
    snn_conv_lif<<<grid, block, 0, stream>>>(x, w, gamma, beta, mean, var, out);
}

// Round 4
// 1110.210 us; speedup vs baseline: 1.6606x; 1.2040x over previous
//
#include <hip/hip_runtime.h>

// Fused Conv1d(k=3,pad=1) + BN(inference) + 4-step LIF + residual.
// x: (L=2048, TB=128, D=128) f32. conv_w: (D,D,3). out: (L,TB,D) f32.
//
// R6: R3 base (t outer, xs full-row staging — proven access pattern) with the
// ws LDS path DELETED. Weights go global->register: each thread loads its own
// two o-rows' 4-channel slice (6 float4) per i4-step, pipelined one step
// ahead (L1-hot: all 4 waves read identical addresses). Removes both per-it
// barriers (128 -> 8 per block), all ws staging, and all per-lane conflicted
// ds_reads (xs reads are same-address broadcasts). FMA order bit-identical
// to R3 (absmax must stay 0.0).

constexpr int L   = 2048;
constexpr int NTB = 128;
constexpr int D   = 128;
constexpr int T   = 4;
constexpr int LT  = 64;        // l-tile per block (4 waves x JT)
constexpr int NP  = LT + 2;    // 66 staged positions (halo)
constexpr int JT  = 16;        // l-positions per thread

__global__ __launch_bounds__(256, 3)
void snn_conv_lif(const float* __restrict__ x, const float* __restrict__ w,
                  const float* __restrict__ gamma, const float* __restrict__ beta,
                  const float* __restrict__ mean, const float* __restrict__ var,
                  float* __restrict__ out) {
    __shared__ float xs[NP * D];      // 33792 B (total LDS)

    const int tid = threadIdx.x;
    const int b   = blockIdx.x & 31;
    const int lt  = blockIdx.x >> 5;
    const int l0  = lt * LT;
    const int q   = tid & 63;          // o-pair index
    const int lh  = tid >> 6;          // wave index
    const int p0  = lh * JT;

    const int o0 = 2 * q, o1 = o0 + 1;
    const float sc0 = gamma[o0] / sqrtf(var[o0] + 1e-5f);
    const float bi0 = beta[o0] - mean[o0] * sc0;
    const float sc1 = gamma[o1] / sqrtf(var[o1] + 1e-5f);
    const float bi1 = beta[o1] - mean[o1] * sc1;

    // this thread's two weight rows; per i4-step ii (0..31) the slice is
    // w[o][ii*4 .. ii*4+4)[k=0..3) = floats [o*384 + ii*12, +12) = 3 float4
    const float* w0 = w + o0 * (D * 3);
    const float* w1 = w + o1 * (D * 3);

    float v0[JT], v1[JT];
    #pragma unroll
    for (int j = 0; j < JT; ++j) { v0[j] = 0.f; v1[j] = 0.f; }

    #pragma unroll 1
    for (int t = 0; t < T; ++t) {
        const int n = t * 32 + b;
        __syncthreads();   // protect xs from previous epilogue readers
        // ---- stage x[l0-1 .. l0+LT][n][:] into xs[pos][i] (full rows) ----
        for (int idx = tid; idx < NP * 32; idx += 256) {
            const int p = idx >> 5, c = idx & 31;
            const int l = l0 - 1 + p;
            float4 val = make_float4(0.f, 0.f, 0.f, 0.f);
            if (l >= 0 && l < L)
                val = ((const float4*)x)[(l * NTB + n) * (D / 4) + c];
            ((float4*)xs)[p * (D / 4) + c] = val;
        }

        float a0[JT], a1[JT];
        #pragma unroll
        for (int j = 0; j < JT; ++j) { a0[j] = 0.f; a1[j] = 0.f; }

        // prefetch weights for ii=0 (overlaps with staging + barrier)
        float4 wcA0 = *((const float4*)(w0 + 0));
        float4 wcA1 = *((const float4*)(w0 + 4));
        float4 wcA2 = *((const float4*)(w0 + 8));
        float4 wcB0 = *((const float4*)(w1 + 0));
        float4 wcB1 = *((const float4*)(w1 + 4));
        float4 wcB2 = *((const float4*)(w1 + 8));
        __syncthreads();   // xs ready

        #pragma unroll 2
        for (int ii = 0; ii < 32; ++ii) {
            // ---- prefetch next i4-step's weights (consumed 384 FMAs later) ----
            float4 wnA0, wnA1, wnA2, wnB0, wnB1, wnB2;
            if (ii < 31) {
                const float* pa = w0 + (ii + 1) * 12;
                const float* pb = w1 + (ii + 1) * 12;
                wnA0 = *((const float4*)(pa));
                wnA1 = *((const float4*)(pa + 4));
                wnA2 = *((const float4*)(pa + 8));
                wnB0 = *((const float4*)(pb));
                wnB1 = *((const float4*)(pb + 4));
                wnB2 = *((const float4*)(pb + 8));
            }

            const float wA[12] = {wcA0.x, wcA0.y, wcA0.z, wcA0.w,
                                  wcA1.x, wcA1.y, wcA1.z, wcA1.w,
                                  wcA2.x, wcA2.y, wcA2.z, wcA2.w};
            const float wB[12] = {wcB0.x, wcB0.y, wcB0.z, wcB0.w,
                                  wcB1.x, wcB1.y, wcB1.z, wcB1.w,
                                  wcB2.x, wcB2.y, wcB2.z, wcB2.w};

            const float4* xcol = (const float4*)xs + ii;   // channel-group ii
            float4 xa = xcol[(p0 + 0) * (D / 4)];
            float4 xb = xcol[(p0 + 1) * (D / 4)];
            #pragma unroll
            for (int j = 0; j < JT; ++j) {
                const float4 xc = xcol[(p0 + j + 2) * (D / 4)];
                float s0 = a0[j];
                float s1 = a1[j];
                s0 = fmaf(xa.x, wA[0], s0);   s1 = fmaf(xa.x, wB[0], s1);   // k=0,i+0
                s0 = fmaf(xa.y, wA[3], s0);   s1 = fmaf(xa.y, wB[3], s1);   // k=0,i+1
                s0 = fmaf(xa.z, wA[6], s0);   s1 = fmaf(xa.z, wB[6], s1);
                s0 = fmaf(xa.w, wA[9], s0);   s1 = fmaf(xa.w, wB[9], s1);
                s0 = fmaf(xb.x, wA[1], s0);   s1 = fmaf(xb.x, wB[1], s1);   // k=1
                s0 = fmaf(xb.y, wA[4], s0);   s1 = fmaf(xb.y, wB[4], s1);
                s0 = fmaf(xb.z, wA[7], s0);   s1 = fmaf(xb.z, wB[7], s1);
                s0 = fmaf(xb.w, wA[10], s0);  s1 = fmaf(xb.w, wB[10], s1);
                s0 = fmaf(xc.x, wA[2], s0);   s1 = fmaf(xc.x, wB[2], s1);   // k=2
                s0 = fmaf(xc.y, wA[5], s0);   s1 = fmaf(xc.y, wB[5], s1);
                s0 = fmaf(xc.z, wA[8], s0);   s1 = fmaf(xc.z, wB[8], s1);
                s0 = fmaf(xc.w, wA[11], s0);  s1 = fmaf(xc.w, wB[11], s1);
                a0[j] = s0; a1[j] = s1;
                xa = xb; xb = xc;
            }

            // rotate pipeline regs (renamed away by the unroll-2 bodies)
            wcA0 = wnA0; wcA1 = wnA1; wcA2 = wnA2;
            wcB0 = wnB0; wcB1 = wnB1; wcB2 = wnB2;
        }

        // ---- BN + LIF step + residual + store (float2 over the o-pair) ----
        #pragma unroll
        for (int j = 0; j < JT; ++j) {
            const float y0 = fmaf(a0[j], sc0, bi0);
            const float y1 = fmaf(a1[j], sc1, bi1);
            const float h0 = 0.5f * (v0[j] + y0);      // v + (y - v)/tau, tau=2
            const float h1 = 0.5f * (v1[j] + y1);
            const bool f0 = (h0 >= 1.0f);
            const bool f1 = (h1 >= 1.0f);
            v0[j] = f0 ? 0.0f : h0;                    // hard reset
            v1[j] = f1 ? 0.0f : h1;
            const int l = l0 + p0 + j;
            const float2 res = ((const float2*)xs)[(p0 + j + 1) * (D / 2) + q];
            float2 ov;
            ov.x = res.x + (f0 ? 1.0f : 0.0f);
            ov.y = res.y + (f1 ? 1.0f : 0.0f);
            ((float2*)out)[(l * NTB + n) * (D / 2) + q] = ov;
        }
    }
}

extern "C" void kernel_launch(void* const* d_in, const int* in_sizes, int n_in,
                              void* d_out, int out_size, void* d_ws, size_t ws_size,
                              hipStream_t stream) {
    const float* x     = (const float*)d_in[0];
    const float* w     = (const float*)d_in[1];
    const float* gamma = (const float*)d_in[2];
    const float* beta  = (const float*)d_in[3];
    const float* mean  = (const float*)d_in[4];
    const float* var   = (const float*)d_in[5];
    float* out = (float*)d_out;

    dim3 grid((L / LT) * 32);   // 32 l-tiles x 32 b values = 1024 blocks
    dim3 block(256);
    snn_conv_lif<<<grid, block, 0, stream>>>(x, w, gamma, beta, mean, var, out);
}

// Round 5
// 578.889 us; speedup vs baseline: 3.1847x; 1.9178x over previous
//
#include <hip/hip_runtime.h>

// Fused Conv1d(k=3,pad=1) + BN(inference) + 4-step LIF + residual.
// x: (L=2048, TB=128, D=128) f32. conv_w: (D,D,3). out: (L,TB,D) f32.
//
// R7 = R3 base (t outer, xs full-row LDS staging, ws via LDS) with:
//  (a) ob=4: 32 lanes cover o-quads, lane-bit 5 covers 2 l-groups -> each
//      wave-level xs read serves both groups (2-addr = conflict-free) and
//      feeds 4 independent acc chains (48 FMA per xc read).
//  (b) ws transposed to [c][q4] float4 layout: per-lane reads are
//      lane-consecutive 16 B -> zero bank conflicts (was ~8-way at WROW=52).
//  (c) float4 coalesced output stores.
// Per-o FMA order identical to R3 (absmax must stay 0.0).

constexpr int L   = 2048;
constexpr int NTB = 128;
constexpr int D   = 128;
constexpr int T   = 4;
constexpr int LT  = 64;        // l-tile per block
constexpr int NP  = LT + 2;    // 66 staged positions (halo)
constexpr int JT  = 8;         // l-positions per thread (2 groups x 8 per wave)

__global__ __launch_bounds__(256, 3)
void snn_conv_lif(const float* __restrict__ x, const float* __restrict__ w,
                  const float* __restrict__ gamma, const float* __restrict__ beta,
                  const float* __restrict__ mean, const float* __restrict__ var,
                  float* __restrict__ out) {
    __shared__ float xs[NP * D];        // 33792 B
    __shared__ float ws[24 * 32 * 4];   // 12288 B: [oo*6+f][q4] float4  (total 46080 B)

    const int tid = threadIdx.x;
    const int b   = blockIdx.x & 31;
    const int lt  = blockIdx.x >> 5;
    const int l0  = lt * LT;
    const int q4  = tid & 31;                              // o-quad: o = 4*q4..4*q4+3
    const int p0  = (tid >> 6) * 16 + ((tid >> 5) & 1) * JT;  // l-group base

    float sc[4], bi[4];
    {
        const float4 g4 = ((const float4*)gamma)[q4];
        const float4 b4 = ((const float4*)beta)[q4];
        const float4 m4 = ((const float4*)mean)[q4];
        const float4 v4 = ((const float4*)var)[q4];
        const float gg[4] = {g4.x, g4.y, g4.z, g4.w};
        const float bb[4] = {b4.x, b4.y, b4.z, b4.w};
        const float mm[4] = {m4.x, m4.y, m4.z, m4.w};
        const float vv[4] = {v4.x, v4.y, v4.z, v4.w};
        #pragma unroll
        for (int oo = 0; oo < 4; ++oo) {
            sc[oo] = gg[oo] / sqrtf(vv[oo] + 1e-5f);
            bi[oo] = bb[oo] - mm[oo] * sc[oo];
        }
    }

    float v[4][JT];
    #pragma unroll
    for (int oo = 0; oo < 4; ++oo)
        #pragma unroll
        for (int j = 0; j < JT; ++j) v[oo][j] = 0.f;

    #pragma unroll 1
    for (int t = 0; t < T; ++t) {
        const int n = t * 32 + b;
        __syncthreads();   // protect xs from previous epilogue readers
        // ---- stage x[l0-1 .. l0+LT][n][:] into xs[pos][i] (full rows) ----
        for (int idx = tid; idx < NP * 32; idx += 256) {
            const int p = idx >> 5, c = idx & 31;
            const int l = l0 - 1 + p;
            float4 val = make_float4(0.f, 0.f, 0.f, 0.f);
            if (l >= 0 && l < L)
                val = ((const float4*)x)[(l * NTB + n) * (D / 4) + c];
            ((float4*)xs)[p * (D / 4) + c] = val;
        }

        float a[4][JT];
        #pragma unroll
        for (int oo = 0; oo < 4; ++oo)
            #pragma unroll
            for (int j = 0; j < JT; ++j) a[oo][j] = 0.f;

        #pragma unroll 1
        for (int it = 0; it < 16; ++it) {
            __syncthreads();  // previous tile's ws readers done (also covers xs at it==0)
            // ---- stage weight tile, transposed: ws[(oo*6+f)*32 + q] ----
            #pragma unroll
            for (int r = 0; r < 3; ++r) {
                const int idx = tid + r * 256;
                const int qq  = idx & 31;
                const int cc  = idx >> 5;          // 0..23
                const int f   = cc >> 2;           // 0..5
                const int oo  = cc & 3;            // 0..3
                const float4 wv = *((const float4*)(w + (4 * qq + oo) * (D * 3) + it * 24 + f * 4));
                *((float4*)(ws + ((oo * 6 + f) * 32 + qq) * 4)) = wv;
            }
            __syncthreads();

            #pragma unroll
            for (int i4 = 0; i4 < 2; ++i4) {
                // per-lane weight fragments: lane-consecutive -> conflict-free
                float4 W0[4], W1[4], W2[4];
                #pragma unroll
                for (int oo = 0; oo < 4; ++oo) {
                    const float* wp = ws + ((oo * 6 + i4 * 3) * 32 + q4) * 4;
                    W0[oo] = *((const float4*)(wp));
                    W1[oo] = *((const float4*)(wp + 128));
                    W2[oo] = *((const float4*)(wp + 256));
                }

                const int ii = it * 2 + i4;
                const float4* xcol = (const float4*)xs + ii;   // channel-group ii
                float4 xa = xcol[(p0 + 0) * 32];
                float4 xb = xcol[(p0 + 1) * 32];
                #pragma unroll
                for (int j = 0; j < JT; ++j) {
                    const float4 xc = xcol[(p0 + j + 2) * 32];
                    #pragma unroll
                    for (int oo = 0; oo < 4; ++oo) {
                        float s = a[oo][j];
                        const float4 w0 = W0[oo], w1 = W1[oo], w2 = W2[oo];
                        s = fmaf(xa.x, w0.x, s);   // k=0, i+0   (wr[0])
                        s = fmaf(xa.y, w0.w, s);   // k=0, i+1   (wr[3])
                        s = fmaf(xa.z, w1.z, s);   // k=0, i+2   (wr[6])
                        s = fmaf(xa.w, w2.y, s);   // k=0, i+3   (wr[9])
                        s = fmaf(xb.x, w0.y, s);   // k=1, i+0   (wr[1])
                        s = fmaf(xb.y, w1.x, s);   // k=1, i+1   (wr[4])
                        s = fmaf(xb.z, w1.w, s);   // k=1, i+2   (wr[7])
                        s = fmaf(xb.w, w2.z, s);   // k=1, i+3   (wr[10])
                        s = fmaf(xc.x, w0.z, s);   // k=2, i+0   (wr[2])
                        s = fmaf(xc.y, w1.y, s);   // k=2, i+1   (wr[5])
                        s = fmaf(xc.z, w2.x, s);   // k=2, i+2   (wr[8])
                        s = fmaf(xc.w, w2.w, s);   // k=2, i+3   (wr[11])
                        a[oo][j] = s;
                    }
                    xa = xb; xb = xc;
                }
            }
        }

        // ---- BN + LIF step + residual + store (float4 over the o-quad) ----
        #pragma unroll
        for (int j = 0; j < JT; ++j) {
            const float4 res = ((const float4*)xs)[(p0 + j + 1) * 32 + q4];
            const float rr[4] = {res.x, res.y, res.z, res.w};
            float ov[4];
            #pragma unroll
            for (int oo = 0; oo < 4; ++oo) {
                const float y = fmaf(a[oo][j], sc[oo], bi[oo]);
                const float h = 0.5f * (v[oo][j] + y);     // v + (y - v)/tau, tau=2
                const bool fire = (h >= 1.0f);
                v[oo][j] = fire ? 0.0f : h;                // hard reset
                ov[oo] = rr[oo] + (fire ? 1.0f : 0.0f);
            }
            const int l = l0 + p0 + j;
            ((float4*)out)[(l * NTB + n) * 32 + q4] =
                make_float4(ov[0], ov[1], ov[2], ov[3]);
        }
    }
}

extern "C" void kernel_launch(void* const* d_in, const int* in_sizes, int n_in,
                              void* d_out, int out_size, void* d_ws, size_t ws_size,
                              hipStream_t stream) {
    const float* x     = (const float*)d_in[0];
    const float* w     = (const float*)d_in[1];
    const float* gamma = (const float*)d_in[2];
    const float* beta  = (const float*)d_in[3];
    const float* mean  = (const float*)d_in[4];
    const float* var   = (const float*)d_in[5];
    float* out = (float*)d_out;

    dim3 grid((L / LT) * 32);   // 32 l-tiles x 32 b values = 1024 blocks
    dim3 block(256);
    snn_conv_lif<<<grid, block, 0, stream>>>(x, w, gamma, beta, mean, var, out);
}

// Round 6
// 568.963 us; speedup vs baseline: 3.2402x; 1.0174x over previous
//
#include <hip/hip_runtime.h>

// Fused Conv1d(k=3,pad=1) + BN(inference) + 4-step LIF + residual.
// x: (L=2048, TB=128, D=128) f32. conv_w: (D,D,3). out: (L,TB,D) f32.
//
// R8 = R7 with the register tile doubled: JT 8->16, LT 64->128.
// Per i4-step: 30 LDS reads feed 768 thread-FMAs (25.6 FMA/read, was 17.5).
// At 2 blocks/CU (78.8 KB LDS) both the LDS pipe (~94%) and the FMA pipe
// (~100%) are modeled near-saturation. Grid = 512 blocks = exactly 2/CU.
// launch_bounds(256,2) gives a 256-VGPR budget (est. usage ~210, no spill).
// Per-o FMA order identical to R3/R7 (absmax must stay 0.0).

constexpr int L   = 2048;
constexpr int NTB = 128;
constexpr int D   = 128;
constexpr int T   = 4;
constexpr int LT  = 128;       // l-tile per block (8 l-groups x JT)
constexpr int NP  = LT + 2;    // 130 staged positions (halo)
constexpr int JT  = 16;        // l-positions per thread

__global__ __launch_bounds__(256, 2)
void snn_conv_lif(const float* __restrict__ x, const float* __restrict__ w,
                  const float* __restrict__ gamma, const float* __restrict__ beta,
                  const float* __restrict__ mean, const float* __restrict__ var,
                  float* __restrict__ out) {
    __shared__ float xs[NP * D];        // 66560 B
    __shared__ float ws[24 * 32 * 4];   // 12288 B: [oo*6+f][q4] float4  (total 78848 B)

    const int tid = threadIdx.x;
    const int b   = blockIdx.x & 31;
    const int lt  = blockIdx.x >> 5;
    const int l0  = lt * LT;
    const int q4  = tid & 31;            // o-quad: o = 4*q4..4*q4+3
    const int p0  = (tid >> 5) * JT;     // l-group base: (0..7)*16

    float sc[4], bi[4];
    {
        const float4 g4 = ((const float4*)gamma)[q4];
        const float4 b4 = ((const float4*)beta)[q4];
        const float4 m4 = ((const float4*)mean)[q4];
        const float4 v4 = ((const float4*)var)[q4];
        const float gg[4] = {g4.x, g4.y, g4.z, g4.w};
        const float bb[4] = {b4.x, b4.y, b4.z, b4.w};
        const float mm[4] = {m4.x, m4.y, m4.z, m4.w};
        const float vv[4] = {v4.x, v4.y, v4.z, v4.w};
        #pragma unroll
        for (int oo = 0; oo < 4; ++oo) {
            sc[oo] = gg[oo] / sqrtf(vv[oo] + 1e-5f);
            bi[oo] = bb[oo] - mm[oo] * sc[oo];
        }
    }

    float v[4][JT];
    #pragma unroll
    for (int oo = 0; oo < 4; ++oo)
        #pragma unroll
        for (int j = 0; j < JT; ++j) v[oo][j] = 0.f;

    #pragma unroll 1
    for (int t = 0; t < T; ++t) {
        const int n = t * 32 + b;
        __syncthreads();   // protect xs from previous epilogue readers
        // ---- stage x[l0-1 .. l0+LT][n][:] into xs[pos][i] (full rows) ----
        for (int idx = tid; idx < NP * 32; idx += 256) {
            const int p = idx >> 5, c = idx & 31;
            const int l = l0 - 1 + p;
            float4 val = make_float4(0.f, 0.f, 0.f, 0.f);
            if (l >= 0 && l < L)
                val = ((const float4*)x)[(l * NTB + n) * (D / 4) + c];
            ((float4*)xs)[p * (D / 4) + c] = val;
        }

        float a[4][JT];
        #pragma unroll
        for (int oo = 0; oo < 4; ++oo)
            #pragma unroll
            for (int j = 0; j < JT; ++j) a[oo][j] = 0.f;

        #pragma unroll 1
        for (int it = 0; it < 16; ++it) {
            __syncthreads();  // previous tile's ws readers done (covers xs at it==0)
            // ---- stage weight tile, transposed: ws[(oo*6+f)*32 + q] ----
            #pragma unroll
            for (int r = 0; r < 3; ++r) {
                const int idx = tid + r * 256;
                const int qq  = idx & 31;
                const int cc  = idx >> 5;          // 0..23
                const int f   = cc >> 2;           // 0..5
                const int oo  = cc & 3;            // 0..3
                const float4 wv = *((const float4*)(w + (4 * qq + oo) * (D * 3) + it * 24 + f * 4));
                *((float4*)(ws + ((oo * 6 + f) * 32 + qq) * 4)) = wv;
            }
            __syncthreads();

            #pragma unroll
            for (int i4 = 0; i4 < 2; ++i4) {
                // per-lane weight fragments: lane-consecutive -> conflict-free
                float4 W0[4], W1[4], W2[4];
                #pragma unroll
                for (int oo = 0; oo < 4; ++oo) {
                    const float* wp = ws + ((oo * 6 + i4 * 3) * 32 + q4) * 4;
                    W0[oo] = *((const float4*)(wp));
                    W1[oo] = *((const float4*)(wp + 128));
                    W2[oo] = *((const float4*)(wp + 256));
                }

                const int ii = it * 2 + i4;
                const float4* xcol = (const float4*)xs + ii;   // channel-group ii
                float4 xa = xcol[(p0 + 0) * 32];
                float4 xb = xcol[(p0 + 1) * 32];
                #pragma unroll
                for (int j = 0; j < JT; ++j) {
                    const float4 xc = xcol[(p0 + j + 2) * 32];
                    #pragma unroll
                    for (int oo = 0; oo < 4; ++oo) {
                        float s = a[oo][j];
                        const float4 w0 = W0[oo], w1 = W1[oo], w2 = W2[oo];
                        s = fmaf(xa.x, w0.x, s);   // k=0, i+0
                        s = fmaf(xa.y, w0.w, s);   // k=0, i+1
                        s = fmaf(xa.z, w1.z, s);   // k=0, i+2
                        s = fmaf(xa.w, w2.y, s);   // k=0, i+3
                        s = fmaf(xb.x, w0.y, s);   // k=1, i+0
                        s = fmaf(xb.y, w1.x, s);   // k=1, i+1
                        s = fmaf(xb.z, w1.w, s);   // k=1, i+2
                        s = fmaf(xb.w, w2.z, s);   // k=1, i+3
                        s = fmaf(xc.x, w0.z, s);   // k=2, i+0
                        s = fmaf(xc.y, w1.y, s);   // k=2, i+1
                        s = fmaf(xc.z, w2.x, s);   // k=2, i+2
                        s = fmaf(xc.w, w2.w, s);   // k=2, i+3
                        a[oo][j] = s;
                    }
                    xa = xb; xb = xc;
                }
            }
        }

        // ---- BN + LIF step + residual + store (float4 over the o-quad) ----
        #pragma unroll
        for (int j = 0; j < JT; ++j) {
            const float4 res = ((const float4*)xs)[(p0 + j + 1) * 32 + q4];
            const float rr[4] = {res.x, res.y, res.z, res.w};
            float ov[4];
            #pragma unroll
            for (int oo = 0; oo < 4; ++oo) {
                const float y = fmaf(a[oo][j], sc[oo], bi[oo]);
                const float h = 0.5f * (v[oo][j] + y);     // v + (y - v)/tau, tau=2
                const bool fire = (h >= 1.0f);
                v[oo][j] = fire ? 0.0f : h;                // hard reset
                ov[oo] = rr[oo] + (fire ? 1.0f : 0.0f);
            }
            const int l = l0 + p0 + j;
            ((float4*)out)[(l * NTB + n) * 32 + q4] =
                make_float4(ov[0], ov[1], ov[2], ov[3]);
        }
    }
}

extern "C" void kernel_launch(void* const* d_in, const int* in_sizes, int n_in,
                              void* d_out, int out_size, void* d_ws, size_t ws_size,
                              hipStream_t stream) {
    const float* x     = (const float*)d_in[0];
    const float* w     = (const float*)d_in[1];
    const float* gamma = (const float*)d_in[2];
    const float* beta  = (const float*)d_in[3];
    const float* mean  = (const float*)d_in[4];
    const float* var   = (const float*)d_in[5];
    float* out = (float*)d_out;

    dim3 grid((L / LT) * 32);   // 16 l-tiles x 32 b values = 512 blocks (2/CU)
    dim3 block(256);
    snn_conv_lif<<<grid, block, 0, stream>>>(x, w, gamma, beta, mean, var, out);
}